// Round 4
// baseline (173.106 us; speedup 1.0000x reference)
//
#include <hip/hip_runtime.h>
#include <math.h>

#define NELEC 10
#define NSPIN 2
#define NPER 5
#define DIM 3
#define NION 2
#define DP 32
#define NDENSE 64
#define NPERM 120
#define RS 324   // G row stride (words): the 5 selectable rows land on disjoint bank quads.
#define W1OFF (160 + NPER * RS)               // w1L base (words) = 1780
#define POOL_WORDS (W1OFF + NDENSE * NDENSE)  // 1780 + 4096 = 5876 words/spin (~23.5 KB)

// R19: lane-owns-perm GEMM. Stage-3 transpose machinery deleted: each lane keeps its
// h[64] in registers (as 32 v2f pairs) and computes V[p][:] itself in 4 j-quarters.
// W1 is wave-uniform -> staged to LDS once, read as broadcast ds_read_b128 (no L2
// latency in the inner loop, no bank conflicts). Per-element FMA order k-ascending ==
// R13 bit-identical. Block LDS ~47 KB -> 3 WG/CU; stage 3 has ZERO barriers.

typedef float v2f __attribute__((ext_vector_type(2)));
typedef float v4f __attribute__((ext_vector_type(4)));

// Packed fp32 FMA (VOP3P), same encoding family as the R12-validated LO/HI macros,
// but broadcasting the H operand (src0) instead of selecting the W half:
//   BL: acc.{lo,hi} += h.lo * w.{lo,hi}   (op_sel_hi[0]=0 -> hi result uses src0.lo)
//   BH: acc.{lo,hi} += h.hi * w.{lo,hi}   (op_sel[0]=1, op_sel_hi[0]=1 -> both use src0.hi)
#define PK_FMA_BL(acc, hp, wp) \
    asm("v_pk_fma_f32 %0, %1, %2, %0 op_sel_hi:[0,1,1]" : "+v"(acc) : "v"(hp), "v"(wp))
#define PK_FMA_BH(acc, hp, wp) \
    asm("v_pk_fma_f32 %0, %1, %2, %0 op_sel:[1,0,0] op_sel_hi:[1,1,1]" : "+v"(acc) : "v"(hp), "v"(wp))

// tanh(x) = 1 - 2*rcp(exp(2x)+1): ~1-2 ulp, exact at saturation. Validated R5-R18.
__device__ __forceinline__ float fast_tanh(float x) {
    float e = __expf(2.0f * x);
    return 1.0f - 2.0f * __builtin_amdgcn_rcpf(e + 1.0f);
}

__device__ __forceinline__ unsigned pick_remove(unsigned& el, int d) {
    unsigned v = (el >> (4 * d)) & 0xFu;
    unsigned low = el & ((1u << (4 * d)) - 1u);
    el = low | ((el >> (4 * (d + 1))) << (4 * d));
    return v;
}

// ---------------- fused: one block per batch element, 4 waves = 2 spin-pairs ----------------
// Waves 0-1: spin 0 perms 0-59 / 60-119; waves 2-3: same for spin 1. Lanes 60-63 idle
// (sign=0; they compute finite garbage that contributes exactly 0).
__global__ __launch_bounds__(256, 1) __attribute__((amdgpu_num_vgpr(128)))
void antisym_fused(
    const float* __restrict__ elec_pos, const float* __restrict__ ion_pos,
    const float* __restrict__ bf_w, const float* __restrict__ bf_b,
    const float* __restrict__ w0, const float* __restrict__ b0,
    const float* __restrict__ w1, const float* __restrict__ b1,
    const float* __restrict__ w2, const float* __restrict__ jk,
    float* __restrict__ out, int B)
{
    const int b = blockIdx.x;
    const int t = threadIdx.x;
    const int s = t >> 7;                   // spin: waves 0-1 -> 0, waves 2-3 -> 1
    const int ts = t & 127;                 // thread within the spin-pair
    const int wave = (t >> 6) & 1;          // wave within the spin-pair
    const int lane = t & 63;

    __shared__ __align__(16) float pool[NSPIN][POOL_WORDS];   // 2 x 23504 B
    __shared__ double red[NSPIN][2];
    __shared__ float jterm[2 * NELEC];

    float* s1e = pool[s];                                     // [160]
    #define GROW(j) (pool[s] + 160 + (j) * RS)                // G[j][.]
    float* w1L = pool[s] + W1OFF;                             // [64][64] this spin's W1

    // ---- stage 1: stream_1e = tanh(feats @ bf_w + bf_b), this spin's 5 electrons ----
    const float* ep = elec_pos + (b * NELEC + s * NPER) * DIM;
    const float i0x = ion_pos[0], i0y = ion_pos[1], i0z = ion_pos[2];
    const float i1x = ion_pos[3], i1y = ion_pos[4], i1z = ion_pos[5];
    for (int idx = ts; idx < NPER * DP; idx += 128) {
        int j = idx >> 5, c = idx & 31;
        float ex = ep[j * 3 + 0], ey = ep[j * 3 + 1], ez = ep[j * 3 + 2];
        float dx0 = ex - i0x, dy0 = ey - i0y, dz0 = ez - i0z;
        float dx1 = ex - i1x, dy1 = ey - i1y, dz1 = ez - i1z;
        float n0 = sqrtf(dx0 * dx0 + dy0 * dy0 + dz0 * dz0);
        float n1 = sqrtf(dx1 * dx1 + dy1 * dy1 + dz1 * dz1);
        float acc = bf_b[c];
        acc += dx0 * bf_w[0 * DP + c];
        acc += dy0 * bf_w[1 * DP + c];
        acc += dz0 * bf_w[2 * DP + c];
        acc += dx1 * bf_w[3 * DP + c];
        acc += dy1 * bf_w[4 * DP + c];
        acc += dz1 * bf_w[5 * DP + c];
        acc += n0 * bf_w[6 * DP + c];
        acc += n1 * bf_w[7 * DP + c];
        s1e[idx] = fast_tanh(acc);
    }
    // w1 -> LDS staging (this spin's 16 KB; 8 float4 per thread, L2-hot across blocks)
    {
        const float* w1g = w1 + s * NDENSE * NDENSE;
        for (int idx = ts; idx < (NDENSE * NDENSE) / 4; idx += 128)
            ((float4*)w1L)[idx] = ((const float4*)w1g)[idx];
    }
    // jastrow terms (combine's exact per-term math; summed e-major by t0 later)
    if (t < 2 * NELEC) {
        int e = t >> 1, ion = t & 1;
        const float* epb = elec_pos + b * NELEC * DIM;
        float ex = epb[e * 3 + 0], ey = epb[e * 3 + 1], ez = epb[e * 3 + 2];
        float ix = ion_pos[ion * 3 + 0], iy = ion_pos[ion * 3 + 1], iz = ion_pos[ion * 3 + 2];
        float dx = ex - ix, dy = ey - iy, dz = ez - iz;
        jterm[t] = jk[ion] * sqrtf(dx * dx + dy * dy + dz * dz);
    }
    __syncthreads();

    // ---- stage 2: G[j][i*64+c] = s1e[j][:] @ w0[s][32i:32i+32, c] ----
    // Slice-outer with wcol[32] in registers (R14-validated): 96 global loads/wave.
    const float* w0s = w0 + s * (NPER * DP) * NDENSE;   // [160][64]
    #pragma unroll
    for (int m = 0; m < 3; m++) {
        const int i = wave + 2 * m;         // wave0: i=0,2,4  wave1: i=1,3 (m=2 skipped)
        if (i < NPER) {                     // wave-uniform branch
            float wcol[DP];
            #pragma unroll
            for (int k = 0; k < DP; k++) wcol[k] = w0s[(i * DP + k) * NDENSE + lane];
            #pragma unroll
            for (int j = 0; j < NPER; j++) {
                float acc = 0.f;
                #pragma unroll
                for (int q = 0; q < 8; q++) {
                    float4 sv = *(const float4*)(s1e + j * DP + q * 4);   // LDS broadcast
                    acc += sv.x * wcol[q * 4 + 0];
                    acc += sv.y * wcol[q * 4 + 1];
                    acc += sv.z * wcol[q * 4 + 2];
                    acc += sv.w * wcol[q * 4 + 3];
                }
                GROW(j)[i * NDENSE + lane] = acc;
            }
        }
    }
    __syncthreads();

    const float* b0s = b0 + s * NDENSE;
    const float* w2s = w2 + s * NDENSE;     // w2 is [s][64][1]
    const float* b1s = b1 + s * NDENSE;

    // ---- stage 3 (barrier-free): lane = perm; h in registers; per-lane GEMM ----
    const int pid = wave * 60 + lane;
    float sign = 0.f;
    int p0 = 0, p1 = 0, p2 = 0, p3 = 0, p4 = 0;
    if (lane < 60) {
        int p = pid;
        unsigned el = 0x43210u;
        int d0 = p / 24; p -= d0 * 24;
        int d1 = p / 6;  p -= d1 * 6;
        int d2 = p / 2;  p -= d2 * 2;
        int d3 = p;
        p0 = pick_remove(el, d0);
        p1 = pick_remove(el, d1);
        p2 = pick_remove(el, d2);
        p3 = pick_remove(el, d3);
        p4 = el & 0xF;
        sign = ((d0 + d1 + d2 + d3) & 1) ? -1.f : 1.f;
    }
    const float* g0 = GROW(p0) + 0 * NDENSE;
    const float* g1 = GROW(p1) + 1 * NDENSE;
    const float* g2 = GROW(p2) + 2 * NDENSE;
    const float* g3 = GROW(p3) + 3 * NDENSE;
    const float* g4 = GROW(p4) + 4 * NDENSE;

    // phase 1: h[64] (packed as 32 v2f) + hdot, ascending cc (R13 order, bit-identical)
    v2f hp2[NDENSE / 2];
    float hdot = 0.f;
    #pragma unroll
    for (int cc = 0; cc < NDENSE / 4; cc++) {
        float4 a = *(const float4*)(b0s + cc * 4);                    // uniform
        float4 q;
        q = *(const float4*)(g0 + cc * 4); a.x += q.x; a.y += q.y; a.z += q.z; a.w += q.w;
        q = *(const float4*)(g1 + cc * 4); a.x += q.x; a.y += q.y; a.z += q.z; a.w += q.w;
        q = *(const float4*)(g2 + cc * 4); a.x += q.x; a.y += q.y; a.z += q.z; a.w += q.w;
        q = *(const float4*)(g3 + cc * 4); a.x += q.x; a.y += q.y; a.z += q.z; a.w += q.w;
        q = *(const float4*)(g4 + cc * 4); a.x += q.x; a.y += q.y; a.z += q.z; a.w += q.w;
        float t0 = fast_tanh(a.x), t1 = fast_tanh(a.y), t2 = fast_tanh(a.z), t3 = fast_tanh(a.w);
        v2f u; u.x = t0; u.y = t1; hp2[2 * cc] = u;
        v2f v; v.x = t2; v.y = t3; hp2[2 * cc + 1] = v;
        hdot += t0 * w2s[cc * 4 + 0] + t1 * w2s[cc * 4 + 1]
              + t2 * w2s[cc * 4 + 2] + t3 * w2s[cc * 4 + 3];
    }

    // phase 2: V[p][:] in 4 j-quarters. Per element: acc_j = fma(h[k], w1[k][j], acc_j)
    // for k = 0..63 ascending -> identical arithmetic to R13's gemm. W1 rows are
    // wave-uniform -> ds_read_b128 broadcasts (0 conflicts). Epilogue per quarter:
    // two 8-j octet sums (old si order), accumulated into f64 (matches old f64 tree
    // granularity -> diffs at f64 rounding level only).
    double jsumd = 0.0;
    #pragma unroll 1
    for (int q = 0; q < 4; ++q) {
        v2f acc[8];
        #pragma unroll
        for (int r = 0; r < 8; r++) acc[r] = (v2f)(0.f);
        const float* wq = w1L + q * 16;
        #pragma unroll
        for (int m = 0; m < 32; m++) {
            const float* r0 = wq + (2 * m) * NDENSE;       // w1 row k=2m (quarter slice)
            const float* r1 = wq + (2 * m + 1) * NDENSE;   // w1 row k=2m+1
            const v2f hp = hp2[m];
            v4f a0 = *(const v4f*)(r0),     a1 = *(const v4f*)(r0 + 4);
            v4f e0 = *(const v4f*)(r1),     e1 = *(const v4f*)(r1 + 4);
            PK_FMA_BL(acc[0], hp, a0.xy);  PK_FMA_BL(acc[1], hp, a0.zw);
            PK_FMA_BL(acc[2], hp, a1.xy);  PK_FMA_BL(acc[3], hp, a1.zw);
            PK_FMA_BH(acc[0], hp, e0.xy);  PK_FMA_BH(acc[1], hp, e0.zw);
            PK_FMA_BH(acc[2], hp, e1.xy);  PK_FMA_BH(acc[3], hp, e1.zw);
            v4f c0 = *(const v4f*)(r0 + 8), c1 = *(const v4f*)(r0 + 12);
            v4f f0 = *(const v4f*)(r1 + 8), f1 = *(const v4f*)(r1 + 12);
            PK_FMA_BL(acc[4], hp, c0.xy);  PK_FMA_BL(acc[5], hp, c0.zw);
            PK_FMA_BL(acc[6], hp, c1.xy);  PK_FMA_BL(acc[7], hp, c1.zw);
            PK_FMA_BH(acc[4], hp, f0.xy);  PK_FMA_BH(acc[5], hp, f0.zw);
            PK_FMA_BH(acc[6], hp, f1.xy);  PK_FMA_BH(acc[7], hp, f1.zw);
        }
        float si0 = 0.f, si1 = 0.f;
        #pragma unroll
        for (int r = 0; r < 8; r++) {
            float v0 = (r & 1) ? acc[r >> 1].y : acc[r >> 1].x;
            si0 = fmaf(fast_tanh(v0 + b1s[q * 16 + r]), w2s[q * 16 + r], si0);
            float v1 = (r & 1) ? acc[4 + (r >> 1)].y : acc[4 + (r >> 1)].x;
            si1 = fmaf(fast_tanh(v1 + b1s[q * 16 + 8 + r]), w2s[q * 16 + 8 + r], si1);
        }
        jsumd += (double)si0;
        jsumd += (double)si1;
    }

    // single f64 reduce: dv = sign * (hdot + jsum); sign=0 kills lanes 60-63
    double dv = (double)(sign * hdot) + (double)sign * jsumd;
    #pragma unroll
    for (int off = 32; off > 0; off >>= 1) dv += __shfl_down(dv, off, 64);
    if (lane == 0) red[s][wave] = dv;
    __syncthreads();

    // ---- inline combine ----
    if (t == 0) {
        float ps0 = (float)(red[0][0] + red[0][1]);
        float ps1 = (float)(red[1][0] + red[1][1]);
        float jas = 0.f;
        #pragma unroll
        for (int i = 0; i < 2 * NELEC; i++) jas += jterm[i];
        out[b] = logf(fabsf(ps0 * ps1)) - jas;
    }
    // b2 omitted: sum_p sign_p = 0 kills it exactly.
}

extern "C" void kernel_launch(void* const* d_in, const int* in_sizes, int n_in,
                              void* d_out, int out_size, void* d_ws, size_t ws_size,
                              hipStream_t stream) {
    const float* elec_pos = (const float*)d_in[0];
    const float* ion_pos  = (const float*)d_in[1];
    const float* bf_w     = (const float*)d_in[2];
    const float* bf_b     = (const float*)d_in[3];
    const float* w0       = (const float*)d_in[4];
    const float* b0       = (const float*)d_in[5];
    const float* w1       = (const float*)d_in[6];
    const float* b1       = (const float*)d_in[7];
    const float* w2       = (const float*)d_in[8];
    const float* jk       = (const float*)d_in[10];
    float* out = (float*)d_out;

    const int B = in_sizes[0] / (NELEC * DIM);   // 2048

    hipLaunchKernelGGL(antisym_fused,
                       dim3(B), dim3(256), 0, stream,
                       elec_pos, ion_pos, bf_w, bf_b, w0, b0, w1, b1, w2, jk, out, B);
}

// Round 5
// 159.623 us; speedup vs baseline: 1.0845x; 1.0845x over previous
//
#include <hip/hip_runtime.h>
#include <math.h>

#define NELEC 10
#define NSPIN 2
#define NPER 5
#define DIM 3
#define NION 2
#define DP 32
#define NDENSE 64
#define NPERM 120
#define RS 324   // G row stride (words): the 5 selectable rows land on disjoint bank quads.
#define HTS 124  // HT row stride (words): reads 2 addrs/bank-quad (free, m136); writes 2/bank free.

// R20: spin-split blocks. One block = one (batch, spin) pair, 128 threads (2 waves).
// Stage pipeline, per-thread instruction stream, LDS layout and overlay are IDENTICAL
// to R13 (best measured, 100us rocprof) -- the only change is that the two spins no
// longer share a block, so:
//   - all 5 __syncthreads convoy 2 waves instead of 4 (dataflow never crossed spins)
//   - block LDS halves: 31.8 KB -> 5 blocks/CU (10 waves/CU vs R13's 8), and blocks
//     are independently schedulable units
// Cross-spin combine (log|ps0*ps1| - jas) moves to a tiny kernel2 via d_ws. jastrow
// is exactly separable by spin (e-major order preserved within each spin).
// Stage A: s1e[160] @ 0, G[5][324] @ 160..1780 | stage B: HT[64][124] @ 0..7936
#define POOL_WORDS (NDENSE * HTS)

typedef float v2f __attribute__((ext_vector_type(2)));
typedef float v4f __attribute__((ext_vector_type(4)));

// Packed fp32 FMA (VOP3P), bit-identical to scalar v_fma pairs (R12-validated).
#define PK_FMA_LO(acc, hp, wp) \
    asm("v_pk_fma_f32 %0, %1, %2, %0 op_sel_hi:[1,0,1]" : "+v"(acc) : "v"(hp), "v"(wp))
#define PK_FMA_HI(acc, hp, wp) \
    asm("v_pk_fma_f32 %0, %1, %2, %0 op_sel:[0,1,0] op_sel_hi:[1,1,1]" : "+v"(acc) : "v"(hp), "v"(wp))

// tanh(x) = 1 - 2*rcp(exp(2x)+1): ~1-2 ulp, exact at saturation. Validated R5-R19.
__device__ __forceinline__ float fast_tanh(float x) {
    float e = __expf(2.0f * x);
    return 1.0f - 2.0f * __builtin_amdgcn_rcpf(e + 1.0f);
}

__device__ __forceinline__ unsigned pick_remove(unsigned& el, int d) {
    unsigned v = (el >> (4 * d)) & 0xFu;
    unsigned low = el & ((1u << (4 * d)) - 1u);
    el = low | ((el >> (4 * (d + 1))) << (4 * d));
    return v;
}

// ---------------- kernel 1: one block per (batch element, spin), 2 waves ----------------
__global__ __launch_bounds__(128, 1) __attribute__((amdgpu_num_vgpr(128)))
void antisym_spin(
    const float* __restrict__ elec_pos, const float* __restrict__ ion_pos,
    const float* __restrict__ bf_w, const float* __restrict__ bf_b,
    const float* __restrict__ w0, const float* __restrict__ b0,
    const float* __restrict__ w1, const float* __restrict__ b1,
    const float* __restrict__ w2, const float* __restrict__ jk,
    float* __restrict__ ws, int B)
{
    const int b = blockIdx.x >> 1;
    const int s = blockIdx.x & 1;           // spin handled by this block
    const int t = threadIdx.x;              // 0..127
    const int wave = t >> 6;                // wave within the block
    const int lane = t & 63;

    __shared__ __align__(16) float pool[POOL_WORDS];   // 31744 B, R13 overlay
    __shared__ double red_h[2];
    __shared__ double red_j[2];
    __shared__ float jterm[2 * NPER];

    float* s1e = pool;                                  // [160]    (stage A)
    #define GROW(j)  (pool + 160 + (j) * RS)            // G[j][.]  (stage A)
    #define HTROW(k) (pool + (k) * HTS)                 // HT[k][.] (stage B)

    // ---- stage 1: stream_1e = tanh(feats @ bf_w + bf_b), this spin's 5 electrons ----
    const float* ep = elec_pos + (b * NELEC + s * NPER) * DIM;
    const float i0x = ion_pos[0], i0y = ion_pos[1], i0z = ion_pos[2];
    const float i1x = ion_pos[3], i1y = ion_pos[4], i1z = ion_pos[5];
    for (int idx = t; idx < NPER * DP; idx += 128) {
        int j = idx >> 5, c = idx & 31;
        float ex = ep[j * 3 + 0], ey = ep[j * 3 + 1], ez = ep[j * 3 + 2];
        float dx0 = ex - i0x, dy0 = ey - i0y, dz0 = ez - i0z;
        float dx1 = ex - i1x, dy1 = ey - i1y, dz1 = ez - i1z;
        float n0 = sqrtf(dx0 * dx0 + dy0 * dy0 + dz0 * dz0);
        float n1 = sqrtf(dx1 * dx1 + dy1 * dy1 + dz1 * dz1);
        float acc = bf_b[c];
        acc += dx0 * bf_w[0 * DP + c];
        acc += dy0 * bf_w[1 * DP + c];
        acc += dz0 * bf_w[2 * DP + c];
        acc += dx1 * bf_w[3 * DP + c];
        acc += dy1 * bf_w[4 * DP + c];
        acc += dz1 * bf_w[5 * DP + c];
        acc += n0 * bf_w[6 * DP + c];
        acc += n1 * bf_w[7 * DP + c];
        s1e[idx] = fast_tanh(acc);
    }
    // jastrow terms for THIS spin's 5 electrons (e-major within spin, exact split)
    if (t < 2 * NPER) {
        int e = s * NPER + (t >> 1), ion = t & 1;
        const float* epb = elec_pos + b * NELEC * DIM;
        float ex = epb[e * 3 + 0], ey = epb[e * 3 + 1], ez = epb[e * 3 + 2];
        float ix = ion_pos[ion * 3 + 0], iy = ion_pos[ion * 3 + 1], iz = ion_pos[ion * 3 + 2];
        float dx = ex - ix, dy = ey - iy, dz = ez - iz;
        jterm[t] = jk[ion] * sqrtf(dx * dx + dy * dy + dz * dz);
    }
    __syncthreads();

    // ---- stage 2: G[j][i*64+c] = s1e[j][:] @ w0[s][32i:32i+32, c] ----
    // Slice-outer with wcol[32] in registers (R14-validated): 96 global loads/wave.
    const float* w0s = w0 + s * (NPER * DP) * NDENSE;   // [160][64]
    #pragma unroll
    for (int m = 0; m < 3; m++) {
        const int i = wave + 2 * m;         // wave0: i=0,2,4  wave1: i=1,3 (m=2 skipped)
        if (i < NPER) {                     // wave-uniform branch
            float wcol[DP];
            #pragma unroll
            for (int k = 0; k < DP; k++) wcol[k] = w0s[(i * DP + k) * NDENSE + lane];
            #pragma unroll
            for (int j = 0; j < NPER; j++) {
                float acc = 0.f;
                #pragma unroll
                for (int q = 0; q < 8; q++) {
                    float4 sv = *(const float4*)(s1e + j * DP + q * 4);   // LDS broadcast
                    acc += sv.x * wcol[q * 4 + 0];
                    acc += sv.y * wcol[q * 4 + 1];
                    acc += sv.z * wcol[q * 4 + 2];
                    acc += sv.w * wcol[q * 4 + 3];
                }
                GROW(j)[i * NDENSE + lane] = acc;
            }
        }
    }
    __syncthreads();

    const float* b0s = b0 + s * NDENSE;
    const float* w2s = w2 + s * NDENSE;     // w2 is [s][64][1]

    // ---- stage 3 phase 1: lane = perm. h_p built in registers (G still live) ----
    const int pid = wave * 60 + lane;
    float sign = 0.f;
    int p0 = 0, p1 = 0, p2 = 0, p3 = 0, p4 = 0;
    if (lane < 60) {
        int p = pid;
        unsigned el = 0x43210u;
        int d0 = p / 24; p -= d0 * 24;
        int d1 = p / 6;  p -= d1 * 6;
        int d2 = p / 2;  p -= d2 * 2;
        int d3 = p;
        p0 = pick_remove(el, d0);
        p1 = pick_remove(el, d1);
        p2 = pick_remove(el, d2);
        p3 = pick_remove(el, d3);
        p4 = el & 0xF;
        sign = ((d0 + d1 + d2 + d3) & 1) ? -1.f : 1.f;
    }
    const float* g0 = GROW(p0) + 0 * NDENSE;
    const float* g1 = GROW(p1) + 1 * NDENSE;
    const float* g2 = GROW(p2) + 2 * NDENSE;
    const float* g3 = GROW(p3) + 3 * NDENSE;
    const float* g4 = GROW(p4) + 4 * NDENSE;

    float h[NDENSE];                        // constant-indexed -> VGPR-resident
    float hdot = 0.f;
    #pragma unroll
    for (int cc = 0; cc < NDENSE / 4; cc++) {
        float4 a = *(const float4*)(b0s + cc * 4);                    // uniform -> s_load
        float4 q;
        q = *(const float4*)(g0 + cc * 4); a.x += q.x; a.y += q.y; a.z += q.z; a.w += q.w;
        q = *(const float4*)(g1 + cc * 4); a.x += q.x; a.y += q.y; a.z += q.z; a.w += q.w;
        q = *(const float4*)(g2 + cc * 4); a.x += q.x; a.y += q.y; a.z += q.z; a.w += q.w;
        q = *(const float4*)(g3 + cc * 4); a.x += q.x; a.y += q.y; a.z += q.z; a.w += q.w;
        q = *(const float4*)(g4 + cc * 4); a.x += q.x; a.y += q.y; a.z += q.z; a.w += q.w;
        float t0 = fast_tanh(a.x), t1 = fast_tanh(a.y), t2 = fast_tanh(a.z), t3 = fast_tanh(a.w);
        h[cc * 4 + 0] = t0; h[cc * 4 + 1] = t1; h[cc * 4 + 2] = t2; h[cc * 4 + 3] = t3;
        hdot += t0 * w2s[cc * 4 + 0] + t1 * w2s[cc * 4 + 1]
              + t2 * w2s[cc * 4 + 2] + t3 * w2s[cc * 4 + 3];
    }

    double dvh = (double)(sign * hdot);     // sign=0 for lanes 60-63
    #pragma unroll
    for (int off = 32; off > 0; off >>= 1) dvh += __shfl_down(dvh, off, 64);
    if (lane == 0) red_h[wave] = dvh;

    __syncthreads();                        // all G reads complete -> pool reusable

    // park h transposed: HT[k][pid] (b32 writes, consecutive pids -> 2 lanes/bank = free)
    if (lane < 60) {
        #pragma unroll
        for (int k = 0; k < NDENSE; k++) HTROW(k)[pid] = h[k];
    }
    __syncthreads();                        // HT visible

    // ---- stage 3 phase 2: 8x8 tile GEMM V[120x64] = H @ W1, packed-fp32 FMA (R12) ----
    const int pg = lane >> 3, jg = lane & 7;
    const int pb = wave ? (56 + 8 * pg) : (8 * pg);
    const float* w1s = w1 + s * NDENSE * NDENSE;
    const float* b1s = b1 + s * NDENSE;
    const float* wgp = w1s + 8 * jg;        // this lane's j-octet in w1 row k

    v2f vp[4][8];
    #pragma unroll
    for (int ip = 0; ip < 4; ip++)
        #pragma unroll
        for (int r = 0; r < 8; r++) vp[ip][r] = (v2f)(0.f);

    v4f ha_n = *(const v4f*)(&HTROW(0)[pb]);
    v4f hb_n = *(const v4f*)(&HTROW(0)[pb + 4]);
    v4f wa_n = *(const v4f*)(wgp);
    v4f wb_n = *(const v4f*)(wgp + 4);
    #pragma unroll 4
    for (int k = 0; k < NDENSE; k++) {
        const v4f ha = ha_n, hb = hb_n, wa = wa_n, wb = wb_n;
        if (k + 1 < NDENSE) {               // R10-validated k+1 prefetch
            ha_n = *(const v4f*)(&HTROW(k + 1)[pb]);
            hb_n = *(const v4f*)(&HTROW(k + 1)[pb + 4]);
            wa_n = *(const v4f*)(wgp + (k + 1) * NDENSE);
            wb_n = *(const v4f*)(wgp + (k + 1) * NDENSE + 4);
        }
        v2f hp[4] = {ha.xy, ha.zw, hb.xy, hb.zw};   // perm pairs
        v2f wp[4] = {wa.xy, wa.zw, wb.xy, wb.zw};   // j pairs
        #pragma unroll
        for (int ip = 0; ip < 4; ip++) {
            PK_FMA_LO(vp[ip][0], hp[ip], wp[0]);
            PK_FMA_HI(vp[ip][1], hp[ip], wp[0]);
            PK_FMA_LO(vp[ip][2], hp[ip], wp[1]);
            PK_FMA_HI(vp[ip][3], hp[ip], wp[1]);
            PK_FMA_LO(vp[ip][4], hp[ip], wp[2]);
            PK_FMA_HI(vp[ip][5], hp[ip], wp[2]);
            PK_FMA_LO(vp[ip][6], hp[ip], wp[3]);
            PK_FMA_HI(vp[ip][7], hp[ip], wp[3]);
        }
    }

    // epilogue: lanesum = sum_i sgn_i * sum_r tanh(v[i][r]+b1[j]) * w2[j]
    float4 b1a = *(const float4*)(b1s + 8 * jg);
    float4 b1b = *(const float4*)(b1s + 8 * jg + 4);
    float4 w2a = *(const float4*)(w2s + 8 * jg);
    float4 w2b = *(const float4*)(w2s + 8 * jg + 4);
    const float b1v[8] = {b1a.x, b1a.y, b1a.z, b1a.w, b1b.x, b1b.y, b1b.z, b1b.w};
    const float w2v[8] = {w2a.x, w2a.y, w2a.z, w2a.w, w2b.x, w2b.y, w2b.z, w2b.w};

    float lanesum = 0.f;
    #pragma unroll
    for (int i = 0; i < 8; i++) {
        int p = pb + i;                      // Lehmer parity
        int d0 = p / 24;  int r0 = p - 24 * d0;
        int d1 = r0 / 6;  int r1 = r0 - 6 * d1;
        int d2 = r1 >> 1; int d3 = r1 & 1;
        float sgn = ((d0 + d1 + d2 + d3) & 1) ? -1.f : 1.f;
        if (wave == 1 && pg == 0) sgn = 0.f; // duplicate tile (perms 56-63)
        float si = 0.f;
        #pragma unroll
        for (int r = 0; r < 8; r++) {
            float vir = (i & 1) ? vp[i >> 1][r].y : vp[i >> 1][r].x;
            si = fmaf(fast_tanh(vir + b1v[r]), w2v[r], si);
        }
        lanesum = fmaf(sgn, si, lanesum);
    }

    double dvj = (double)lanesum;
    #pragma unroll
    for (int off = 32; off > 0; off >>= 1) dvj += __shfl_down(dvj, off, 64);
    if (lane == 0) red_j[wave] = dvj;
    __syncthreads();

    // ---- per-spin partials to workspace ----
    if (t == 0) {
        float ps = (float)((red_h[0] + red_h[1]) + (red_j[0] + red_j[1]));
        float jas = 0.f;
        #pragma unroll
        for (int i = 0; i < 2 * NPER; i++) jas += jterm[i];
        ws[s * B + b] = ps;                 // ps[s][b]
        ws[2 * B + s * B + b] = jas;        // jas[s][b]
    }
    // b2 omitted: sum_p sign_p = 0 kills it exactly.
}

// ---------------- kernel 2: combine (exact R13 math: log|ps0*ps1| - (jas0+jas1)) ----------------
__global__ __launch_bounds__(256) void antisym_combine(
    const float* __restrict__ ws, float* __restrict__ out, int B)
{
    int b = blockIdx.x * blockDim.x + threadIdx.x;
    if (b < B) {
        float ps0 = ws[b];
        float ps1 = ws[B + b];
        float jas = ws[2 * B + b] + ws[3 * B + b];
        out[b] = logf(fabsf(ps0 * ps1)) - jas;
    }
}

extern "C" void kernel_launch(void* const* d_in, const int* in_sizes, int n_in,
                              void* d_out, int out_size, void* d_ws, size_t ws_size,
                              hipStream_t stream) {
    const float* elec_pos = (const float*)d_in[0];
    const float* ion_pos  = (const float*)d_in[1];
    const float* bf_w     = (const float*)d_in[2];
    const float* bf_b     = (const float*)d_in[3];
    const float* w0       = (const float*)d_in[4];
    const float* b0       = (const float*)d_in[5];
    const float* w1       = (const float*)d_in[6];
    const float* b1       = (const float*)d_in[7];
    const float* w2       = (const float*)d_in[8];
    const float* jk       = (const float*)d_in[10];
    float* out = (float*)d_out;
    float* ws  = (float*)d_ws;              // needs 4*B floats = 32 KB

    const int B = in_sizes[0] / (NELEC * DIM);   // 2048

    hipLaunchKernelGGL(antisym_spin,
                       dim3(2 * B), dim3(128), 0, stream,
                       elec_pos, ion_pos, bf_w, bf_b, w0, b0, w1, b1, w2, jk, ws, B);
    hipLaunchKernelGGL(antisym_combine,
                       dim3((B + 255) / 256), dim3(256), 0, stream,
                       ws, out, B);
}

// Round 6
// 154.950 us; speedup vs baseline: 1.1172x; 1.0302x over previous
//
#include <hip/hip_runtime.h>
#include <math.h>

#define NELEC 10
#define NSPIN 2
#define NPER 5
#define DIM 3
#define NION 2
#define DP 32
#define NDENSE 64
#define NPERM 120
#define RS 324   // G row stride (words): the 5 selectable rows land on disjoint bank quads.
#define HTS 124  // HT row stride (words): reads 2 addrs/bank-quad (free, m136); writes 2/bank free.

// Per-spin LDS pool with live-range overlay (R10/R12/R13-validated):
//   stage A: s1e[160] @ 0, G[5][324] @ 160..1780
//   stage B: HT[64][124] @ 0..7936
#define POOL_WORDS (NDENSE * HTS)

typedef float v2f __attribute__((ext_vector_type(2)));
typedef float v4f __attribute__((ext_vector_type(4)));

// Packed fp32 FMA (VOP3P), bit-identical to scalar v_fma pairs (R12-validated).
#define PK_FMA_LO(acc, hp, wp) \
    asm("v_pk_fma_f32 %0, %1, %2, %0 op_sel_hi:[1,0,1]" : "+v"(acc) : "v"(hp), "v"(wp))
#define PK_FMA_HI(acc, hp, wp) \
    asm("v_pk_fma_f32 %0, %1, %2, %0 op_sel:[0,1,0] op_sel_hi:[1,1,1]" : "+v"(acc) : "v"(hp), "v"(wp))

// tanh(x) = 1 - 2*rcp(exp(2x)+1): ~1-2 ulp, exact at saturation. Validated R5-R20.
__device__ __forceinline__ float fast_tanh(float x) {
    float e = __expf(2.0f * x);
    return 1.0f - 2.0f * __builtin_amdgcn_rcpf(e + 1.0f);
}

__device__ __forceinline__ unsigned pick_remove(unsigned& el, int d) {
    unsigned v = (el >> (4 * d)) & 0xFu;
    unsigned low = el & ((1u << (4 * d)) - 1u);
    el = low | ((el >> (4 * (d + 1))) << (4 * d));
    return v;
}

// ---------------- fused: one block per batch element, 4 waves = 2 spin-pairs ----------------
// Base = R13/R0 (100us proven). ONE change (R21): stage-3 GEMM restructured into
// chunk-of-4 double-buffered pipeline. Old loop had depth-1 prefetch = ~64cy cover vs
// ~120cy LDS / ~100-225cy L1-L2 latency on the per-k w1 global loads -> per-step
// waitcnt stalls (the ~37% idle; R17 proved extra waves don't fill it, R10/R17 proved
// prefetch depth matters). New: while 4 k-steps compute from sets E(HT)/X(w1), the
// next chunk loads into F/Y -> 256-512cy prefetch distance. All names static (no
// runtime-indexed arrays -> no scratch). FMA order per vp element k-ascending ->
// bit-identical output. +96 VGPR is free: occupancy is LDS-bound (2 blocks/CU = 2
// waves/SIMD -> 256-VGPR budget). num_vgpr cap intentionally absent (R16 lesson: cap
// games cause spills; R0 had none).
__global__ __launch_bounds__(256, 1) void antisym_fused(
    const float* __restrict__ elec_pos, const float* __restrict__ ion_pos,
    const float* __restrict__ bf_w, const float* __restrict__ bf_b,
    const float* __restrict__ w0, const float* __restrict__ b0,
    const float* __restrict__ w1, const float* __restrict__ b1,
    const float* __restrict__ w2, const float* __restrict__ jk,
    float* __restrict__ out, int B)
{
    const int b = blockIdx.x;
    const int t = threadIdx.x;
    const int s = t >> 7;                   // spin: waves 0-1 -> 0, waves 2-3 -> 1
    const int ts = t & 127;                 // thread within the spin-pair
    const int wave = (t >> 6) & 1;          // wave within the spin-pair
    const int lane = t & 63;

    __shared__ __align__(16) float pool[NSPIN][POOL_WORDS];   // 2 x 31744 B
    __shared__ double red_h[NSPIN][2];
    __shared__ double red_j[NSPIN][2];
    __shared__ float jterm[2 * NELEC];

    float* s1e = pool[s];                                     // [160]    (stage A)
    #define GROW(j) (pool[s] + 160 + (j) * RS)                // G[j][.]  (stage A)
    #define HTROW(k) (pool[s] + (k) * HTS)                    // HT[k][.] (stage B)

    // ---- stage 1: stream_1e = tanh(feats @ bf_w + bf_b), this spin's 5 electrons ----
    const float* ep = elec_pos + (b * NELEC + s * NPER) * DIM;
    const float i0x = ion_pos[0], i0y = ion_pos[1], i0z = ion_pos[2];
    const float i1x = ion_pos[3], i1y = ion_pos[4], i1z = ion_pos[5];
    for (int idx = ts; idx < NPER * DP; idx += 128) {
        int j = idx >> 5, c = idx & 31;
        float ex = ep[j * 3 + 0], ey = ep[j * 3 + 1], ez = ep[j * 3 + 2];
        float dx0 = ex - i0x, dy0 = ey - i0y, dz0 = ez - i0z;
        float dx1 = ex - i1x, dy1 = ey - i1y, dz1 = ez - i1z;
        float n0 = sqrtf(dx0 * dx0 + dy0 * dy0 + dz0 * dz0);
        float n1 = sqrtf(dx1 * dx1 + dy1 * dy1 + dz1 * dz1);
        float acc = bf_b[c];
        acc += dx0 * bf_w[0 * DP + c];
        acc += dy0 * bf_w[1 * DP + c];
        acc += dz0 * bf_w[2 * DP + c];
        acc += dx1 * bf_w[3 * DP + c];
        acc += dy1 * bf_w[4 * DP + c];
        acc += dz1 * bf_w[5 * DP + c];
        acc += n0 * bf_w[6 * DP + c];
        acc += n1 * bf_w[7 * DP + c];
        s1e[idx] = fast_tanh(acc);
    }
    // jastrow terms (combine's exact per-term math; summed e-major by t0 later)
    if (t < 2 * NELEC) {
        int e = t >> 1, ion = t & 1;
        const float* epb = elec_pos + b * NELEC * DIM;
        float ex = epb[e * 3 + 0], ey = epb[e * 3 + 1], ez = epb[e * 3 + 2];
        float ix = ion_pos[ion * 3 + 0], iy = ion_pos[ion * 3 + 1], iz = ion_pos[ion * 3 + 2];
        float dx = ex - ix, dy = ey - iy, dz = ez - iz;
        jterm[t] = jk[ion] * sqrtf(dx * dx + dy * dy + dz * dz);
    }
    __syncthreads();

    // ---- stage 2: G[j][i*64+c] = s1e[j][:] @ w0[s][32i:32i+32, c] ----
    // Slice-outer with wcol[32] in registers (R14-validated): 96 global loads/wave.
    const float* w0s = w0 + s * (NPER * DP) * NDENSE;   // [160][64]
    #pragma unroll
    for (int m = 0; m < 3; m++) {
        const int i = wave + 2 * m;         // wave0: i=0,2,4  wave1: i=1,3 (m=2 skipped)
        if (i < NPER) {                     // wave-uniform branch
            float wcol[DP];
            #pragma unroll
            for (int k = 0; k < DP; k++) wcol[k] = w0s[(i * DP + k) * NDENSE + lane];
            #pragma unroll
            for (int j = 0; j < NPER; j++) {
                float acc = 0.f;
                #pragma unroll
                for (int q = 0; q < 8; q++) {
                    float4 sv = *(const float4*)(s1e + j * DP + q * 4);   // LDS broadcast
                    acc += sv.x * wcol[q * 4 + 0];
                    acc += sv.y * wcol[q * 4 + 1];
                    acc += sv.z * wcol[q * 4 + 2];
                    acc += sv.w * wcol[q * 4 + 3];
                }
                GROW(j)[i * NDENSE + lane] = acc;
            }
        }
    }
    __syncthreads();

    const float* b0s = b0 + s * NDENSE;
    const float* w2s = w2 + s * NDENSE;     // w2 is [s][64][1]

    // ---- stage 3 phase 1: lane = perm. h_p built in registers (G still live) ----
    const int pid = wave * 60 + lane;
    float sign = 0.f;
    int p0 = 0, p1 = 0, p2 = 0, p3 = 0, p4 = 0;
    if (lane < 60) {
        int p = pid;
        unsigned el = 0x43210u;
        int d0 = p / 24; p -= d0 * 24;
        int d1 = p / 6;  p -= d1 * 6;
        int d2 = p / 2;  p -= d2 * 2;
        int d3 = p;
        p0 = pick_remove(el, d0);
        p1 = pick_remove(el, d1);
        p2 = pick_remove(el, d2);
        p3 = pick_remove(el, d3);
        p4 = el & 0xF;
        sign = ((d0 + d1 + d2 + d3) & 1) ? -1.f : 1.f;
    }
    const float* g0 = GROW(p0) + 0 * NDENSE;
    const float* g1 = GROW(p1) + 1 * NDENSE;
    const float* g2 = GROW(p2) + 2 * NDENSE;
    const float* g3 = GROW(p3) + 3 * NDENSE;
    const float* g4 = GROW(p4) + 4 * NDENSE;

    float h[NDENSE];                        // constant-indexed -> VGPR-resident
    float hdot = 0.f;
    #pragma unroll
    for (int cc = 0; cc < NDENSE / 4; cc++) {
        float4 a = *(const float4*)(b0s + cc * 4);                    // uniform -> s_load
        float4 q;
        q = *(const float4*)(g0 + cc * 4); a.x += q.x; a.y += q.y; a.z += q.z; a.w += q.w;
        q = *(const float4*)(g1 + cc * 4); a.x += q.x; a.y += q.y; a.z += q.z; a.w += q.w;
        q = *(const float4*)(g2 + cc * 4); a.x += q.x; a.y += q.y; a.z += q.z; a.w += q.w;
        q = *(const float4*)(g3 + cc * 4); a.x += q.x; a.y += q.y; a.z += q.z; a.w += q.w;
        q = *(const float4*)(g4 + cc * 4); a.x += q.x; a.y += q.y; a.z += q.z; a.w += q.w;
        float t0 = fast_tanh(a.x), t1 = fast_tanh(a.y), t2 = fast_tanh(a.z), t3 = fast_tanh(a.w);
        h[cc * 4 + 0] = t0; h[cc * 4 + 1] = t1; h[cc * 4 + 2] = t2; h[cc * 4 + 3] = t3;
        hdot += t0 * w2s[cc * 4 + 0] + t1 * w2s[cc * 4 + 1]
              + t2 * w2s[cc * 4 + 2] + t3 * w2s[cc * 4 + 3];
    }

    double dvh = (double)(sign * hdot);     // sign=0 for lanes 60-63
    #pragma unroll
    for (int off = 32; off > 0; off >>= 1) dvh += __shfl_down(dvh, off, 64);
    if (lane == 0) red_h[s][wave] = dvh;

    __syncthreads();                        // all G reads complete -> pool reusable

    // park h transposed: HT[k][pid] (b32 writes, consecutive pids -> 2 lanes/bank = free)
    if (lane < 60) {
        #pragma unroll
        for (int k = 0; k < NDENSE; k++) HTROW(k)[pid] = h[k];
    }
    __syncthreads();                        // HT visible

    // ---- stage 3 phase 2: 8x8 tile GEMM V[120x64] = H @ W1 (R21 chunk pipeline) ----
    const int pg = lane >> 3, jg = lane & 7;
    const int pb = wave ? (56 + 8 * pg) : (8 * pg);
    const float* w1s = w1 + s * NDENSE * NDENSE;
    const float* b1s = b1 + s * NDENSE;
    const float* wgp = w1s + 8 * jg;        // this lane's j-octet in w1 row k

    v2f vp[4][8];
    #pragma unroll
    for (int ip = 0; ip < 4; ip++)
        #pragma unroll
        for (int r = 0; r < 8; r++) vp[ip][r] = (v2f)(0.f);

#define LDHT(DA, DB, kk) { DA = *(const v4f*)(&HTROW(kk)[pb]); DB = *(const v4f*)(&HTROW(kk)[pb + 4]); }
#define LDW1(DA, DB, kk) { DA = *(const v4f*)(wgp + (kk) * NDENSE); DB = *(const v4f*)(wgp + (kk) * NDENSE + 4); }
// One k-step: same FMA sequence as R13 (order within a step is irrelevant for
// bit-identity; k order across steps is ascending, matching R13 exactly).
#define STEP(HA, HB, WA, WB) do { \
    v2f hp0 = (HA).xy, hp1 = (HA).zw, hp2 = (HB).xy, hp3 = (HB).zw; \
    v2f wp0 = (WA).xy, wp1 = (WA).zw, wp2 = (WB).xy, wp3 = (WB).zw; \
    PK_FMA_LO(vp[0][0], hp0, wp0); PK_FMA_HI(vp[0][1], hp0, wp0); \
    PK_FMA_LO(vp[0][2], hp0, wp1); PK_FMA_HI(vp[0][3], hp0, wp1); \
    PK_FMA_LO(vp[0][4], hp0, wp2); PK_FMA_HI(vp[0][5], hp0, wp2); \
    PK_FMA_LO(vp[0][6], hp0, wp3); PK_FMA_HI(vp[0][7], hp0, wp3); \
    PK_FMA_LO(vp[1][0], hp1, wp0); PK_FMA_HI(vp[1][1], hp1, wp0); \
    PK_FMA_LO(vp[1][2], hp1, wp1); PK_FMA_HI(vp[1][3], hp1, wp1); \
    PK_FMA_LO(vp[1][4], hp1, wp2); PK_FMA_HI(vp[1][5], hp1, wp2); \
    PK_FMA_LO(vp[1][6], hp1, wp3); PK_FMA_HI(vp[1][7], hp1, wp3); \
    PK_FMA_LO(vp[2][0], hp2, wp0); PK_FMA_HI(vp[2][1], hp2, wp0); \
    PK_FMA_LO(vp[2][2], hp2, wp1); PK_FMA_HI(vp[2][3], hp2, wp1); \
    PK_FMA_LO(vp[2][4], hp2, wp2); PK_FMA_HI(vp[2][5], hp2, wp2); \
    PK_FMA_LO(vp[2][6], hp2, wp3); PK_FMA_HI(vp[2][7], hp2, wp3); \
    PK_FMA_LO(vp[3][0], hp3, wp0); PK_FMA_HI(vp[3][1], hp3, wp0); \
    PK_FMA_LO(vp[3][2], hp3, wp1); PK_FMA_HI(vp[3][3], hp3, wp1); \
    PK_FMA_LO(vp[3][4], hp3, wp2); PK_FMA_HI(vp[3][5], hp3, wp2); \
    PK_FMA_LO(vp[3][6], hp3, wp3); PK_FMA_HI(vp[3][7], hp3, wp3); \
} while (0)

    // Named double-buffered operand sets (all static indexing -> VGPR-resident):
    //   E/F = HT rows (LDS), X/Y = w1 rows (global). While the 4 steps of one chunk
    //   compute, the other chunk's 16 loads are already in flight (256-512cy cover).
    v4f ea0, eb0, ea1, eb1, ea2, eb2, ea3, eb3;
    v4f fa0, fb0, fa1, fb1, fa2, fb2, fa3, fb3;
    v4f xa0, xb0, xa1, xb1, xa2, xb2, xa3, xb3;
    v4f ya0, yb0, ya1, yb1, ya2, yb2, ya3, yb3;

    LDHT(ea0, eb0, 0); LDHT(ea1, eb1, 1); LDHT(ea2, eb2, 2); LDHT(ea3, eb3, 3);
    LDW1(xa0, xb0, 0); LDW1(xa1, xb1, 1); LDW1(xa2, xb2, 2); LDW1(xa3, xb3, 3);

    #pragma unroll 1
    for (int c2 = 0; c2 < 8; c2++) {
        const int k0 = c2 * 8;
        // issue odd chunk's operands (consumed after the 4 even STEPs ~256cy later)
        LDW1(ya0, yb0, k0 + 4); LDW1(ya1, yb1, k0 + 5);
        LDW1(ya2, yb2, k0 + 6); LDW1(ya3, yb3, k0 + 7);
        LDHT(fa0, fb0, k0 + 4); LDHT(fa1, fb1, k0 + 5);
        LDHT(fa2, fb2, k0 + 6); LDHT(fa3, fb3, k0 + 7);
        STEP(ea0, eb0, xa0, xb0); STEP(ea1, eb1, xa1, xb1);
        STEP(ea2, eb2, xa2, xb2); STEP(ea3, eb3, xa3, xb3);
        // issue next even chunk's operands (consumed after the 4 odd STEPs)
        if (c2 < 7) {                       // wave-uniform guard (no OOB w1 reads)
            LDW1(xa0, xb0, k0 + 8);  LDW1(xa1, xb1, k0 + 9);
            LDW1(xa2, xb2, k0 + 10); LDW1(xa3, xb3, k0 + 11);
            LDHT(ea0, eb0, k0 + 8);  LDHT(ea1, eb1, k0 + 9);
            LDHT(ea2, eb2, k0 + 10); LDHT(ea3, eb3, k0 + 11);
        }
        STEP(fa0, fb0, ya0, yb0); STEP(fa1, fb1, ya1, yb1);
        STEP(fa2, fb2, ya2, yb2); STEP(fa3, fb3, ya3, yb3);
    }

    // epilogue: lanesum = sum_i sgn_i * sum_r tanh(v[i][r]+b1[j]) * w2[j]
    float4 b1a = *(const float4*)(b1s + 8 * jg);
    float4 b1b = *(const float4*)(b1s + 8 * jg + 4);
    float4 w2a = *(const float4*)(w2s + 8 * jg);
    float4 w2b = *(const float4*)(w2s + 8 * jg + 4);
    const float b1v[8] = {b1a.x, b1a.y, b1a.z, b1a.w, b1b.x, b1b.y, b1b.z, b1b.w};
    const float w2v[8] = {w2a.x, w2a.y, w2a.z, w2a.w, w2b.x, w2b.y, w2b.z, w2b.w};

    float lanesum = 0.f;
    #pragma unroll
    for (int i = 0; i < 8; i++) {
        int p = pb + i;                      // Lehmer parity
        int d0 = p / 24;  int r0 = p - 24 * d0;
        int d1 = r0 / 6;  int r1 = r0 - 6 * d1;
        int d2 = r1 >> 1; int d3 = r1 & 1;
        float sgn = ((d0 + d1 + d2 + d3) & 1) ? -1.f : 1.f;
        if (wave == 1 && pg == 0) sgn = 0.f; // duplicate tile (perms 56-63)
        float si = 0.f;
        #pragma unroll
        for (int r = 0; r < 8; r++) {
            float vir = (i & 1) ? vp[i >> 1][r].y : vp[i >> 1][r].x;
            si = fmaf(fast_tanh(vir + b1v[r]), w2v[r], si);
        }
        lanesum = fmaf(sgn, si, lanesum);
    }

    double dvj = (double)lanesum;
    #pragma unroll
    for (int off = 32; off > 0; off >>= 1) dvj += __shfl_down(dvj, off, 64);
    if (lane == 0) red_j[s][wave] = dvj;
    __syncthreads();

    // ---- inline combine (R13-validated) ----
    if (t == 0) {
        float ps0 = (float)((red_h[0][0] + red_h[0][1]) + (red_j[0][0] + red_j[0][1]));
        float ps1 = (float)((red_h[1][0] + red_h[1][1]) + (red_j[1][0] + red_j[1][1]));
        float jas = 0.f;
        #pragma unroll
        for (int i = 0; i < 2 * NELEC; i++) jas += jterm[i];
        out[b] = logf(fabsf(ps0 * ps1)) - jas;
    }
    // b2 omitted: sum_p sign_p = 0 kills it exactly.
}

extern "C" void kernel_launch(void* const* d_in, const int* in_sizes, int n_in,
                              void* d_out, int out_size, void* d_ws, size_t ws_size,
                              hipStream_t stream) {
    const float* elec_pos = (const float*)d_in[0];
    const float* ion_pos  = (const float*)d_in[1];
    const float* bf_w     = (const float*)d_in[2];
    const float* bf_b     = (const float*)d_in[3];
    const float* w0       = (const float*)d_in[4];
    const float* b0       = (const float*)d_in[5];
    const float* w1       = (const float*)d_in[6];
    const float* b1       = (const float*)d_in[7];
    const float* w2       = (const float*)d_in[8];
    const float* jk       = (const float*)d_in[10];
    float* out = (float*)d_out;

    const int B = in_sizes[0] / (NELEC * DIM);   // 2048

    hipLaunchKernelGGL(antisym_fused,
                       dim3(B), dim3(256), 0, stream,
                       elec_pos, ion_pos, bf_w, bf_b, w0, b0, w1, b1, w2, jk, out, B);
}